// Round 11
// baseline (407.912 us; speedup 1.0000x reference)
//
#include <hip/hip_runtime.h>

// Rayleigh-Benard tendency kernel, fp32 I/O, fp32 math.
// Layout: state[6][NX][NY][NZ], z contiguous.
//
// R11: x-march pipeline, 64KB-safe. R10's 122KB dynamic LDS needed
// hipFuncSetAttribute inside kernel_launch (graph-capture hostile; suspected
// container killer). Redesign: (1) carry the x-1 plane in REGISTERS (each
// thread's xm stencil values = its own center values from the previous march
// step; 24 VGPRs), so LDS holds only planes P, P+1 + staging target P+2 =
// 3 slots; (2) BYt=4 -> plane = 6 fields x 6 y-rows x 512B = 18KB, 3 slots =
// 55296B STATIC LDS (no attribute, no dynamic arg). Per iter: stage(P+2)
// (global_load_lds: no dest VGPRs, unsinkable) -> store P-1 (aged one phase)
// -> compute P -> __syncthreads (single vmcnt drain per iter, waits on loads
// issued one full compute phase ago). Math value-identical to R3.

namespace {
constexpr int NXc = 256, NYc = 256, NZc = 128;
constexpr int FS = NXc * NYc * NZc;
constexpr int XS = NYc * NZc;
constexpr int YS = NZc;

constexpr float MUc = 1.8e-5f, KTHc = 0.025f, Gc = 9.8f;
constexpr float Rgas = 287.0f;
constexpr float invCV = 1.0f / 717.0f;

constexpr float inv2dx = 128.0f, inv2dy = 128.0f, inv2dz = 63.5f;
constexpr float invdx2 = 65536.0f, invdy2 = 65536.0f, invdz2 = 16129.0f;

constexpr int BYt = 4;                      // y rows computed per block
constexpr int MARCH = 64;                   // x planes marched per block
constexpr int RPP = BYt + 2;                // 6 y rows per field per plane
constexpr int PLANE_ROWS = 6 * RPP;         // 36
constexpr int ROW_B = NZc * 4;              // 512 B
constexpr int PLANE_B = PLANE_ROWS * ROW_B; // 18432 B
constexpr int NSLOT = 3;
constexpr int LDS_B = NSLOT * PLANE_B;      // 55296 B (static, <64KB)

typedef float nf4 __attribute__((ext_vector_type(4)));
typedef const __attribute__((address_space(1))) unsigned int gu32;
typedef __attribute__((address_space(3))) unsigned int lu32;
}

__device__ __forceinline__ void st_nt(float4 v, float4* p) {
    nf4 nv;
    nv.x = v.x; nv.y = v.y; nv.z = v.z; nv.w = v.w;
    __builtin_nontemporal_store(nv, reinterpret_cast<nf4*>(p));
}

#define SLOT(q) (((q) + NSLOT) % NSLOT)

// Stage one x-plane (6 fields x 6 y-rows x 512B = 18KB) into carousel slot.
// 18 global_load_lds per block (2 waves x 9); each stages 2 rows
// (lanes 0-31 -> row 2p, lanes 32-63 -> row 2p+1; LDS dest = base + lane*16).
__device__ __forceinline__ void stage_plane(const char* __restrict__ sb,
                                            char* __restrict__ smem,
                                            int q, int y0, int tx, int ty) {
    const int w = ty >> 1;            // wave id 0..1
    const int h = ty & 1;             // lane-half within wave
    const int gx = q & (NXc - 1);     // periodic x (q may be -1 or >255)
    char* lbase = smem + SLOT(q) * PLANE_B;
    for (int p = w; p < PLANE_ROWS / 2; p += 2) {
        const int R = 2 * p + h;              // LDS row 0..35
        const int f = R / RPP;                // field 0..5
        const int r = R - f * RPP;            // y-row-in-plane 0..5
        const int gy = (y0 + r - 1) & (NYc - 1);
        const char* gp = sb + 4u * ((unsigned)f * FS + (unsigned)gx * XS
                                    + (unsigned)gy * YS) + tx * 16;
        __builtin_amdgcn_global_load_lds((gu32*)gp, (lu32*)(lbase + p * 1024),
                                         16, 0, 0);
    }
}

// LDS read: plane q (carousel), field fi, y-row rr, this thread's z-quad.
#define LROW(q, fi, rr) \
    (*(const float4*)(smem + SLOT(q) * PLANE_B + ((fi) * RPP + (rr)) * ROW_B + tx * 16))

// Neighbors for field q: y-halo + xp from LDS, z-halo via shuffle; xm = prev regs.
#define NEIGH(q, fi) \
    const float4 q##_ym = LROW(P,  fi, ty),     q##_yp = LROW(P,  fi, ty + 2); \
    const float4 q##_xp = LROW(Pp, fi, ty + 1); \
    const float q##_zm = __shfl_up(q##_c.w, 1, 32); \
    const float q##_zp = __shfl_down(q##_c.x, 1, 32);

#define ADV_LAP_C(q, C, PREV, NEXT) \
    adv_##q.C = u_c.C * (q##_xp.C - prev_##q.C) * inv2dx \
              + v_c.C * (q##_yp.C - q##_ym.C) * inv2dy \
              + w_c.C * ((NEXT) - (PREV)) * inv2dz; \
    lap_##q.C = (q##_xp.C + prev_##q.C - 2.0f * q##_c.C) * invdx2 \
              + (q##_yp.C + q##_ym.C - 2.0f * q##_c.C) * invdy2 \
              + ((NEXT) + (PREV) - 2.0f * q##_c.C) * invdz2;

#define DERIVS(q) \
    float4 adv_##q, lap_##q; \
    ADV_LAP_C(q, x, q##_zm,  q##_c.y) \
    ADV_LAP_C(q, y, q##_c.x, q##_c.z) \
    ADV_LAP_C(q, z, q##_c.y, q##_c.w) \
    ADV_LAP_C(q, w, q##_c.z, q##_zp)

__global__ __launch_bounds__(128) void rb_kernel(const float* __restrict__ s,
                                                 float* __restrict__ o) {
    __shared__ char smem[LDS_B];

    const int tx = threadIdx.x;            // z-quad 0..31
    const int ty = threadIdx.y;            // y-row-in-tile 0..3
    const int y0 = blockIdx.x * BYt;
    const int x0 = blockIdx.y * MARCH;
    const int y = y0 + ty;

    const char* sb = (const char*)s;
    float4* o4 = reinterpret_cast<float4*>(o);
    const int fs4 = FS / 4;

    // ---- prologue: stage planes x0-1, x0, x0+1; init prev regs ----
    stage_plane(sb, smem, x0 - 1, y0, tx, ty);
    stage_plane(sb, smem, x0,     y0, tx, ty);
    stage_plane(sb, smem, x0 + 1, y0, tx, ty);
    __syncthreads();

    float4 prev_u = LROW(x0 - 1, 0, ty + 1), prev_v = LROW(x0 - 1, 1, ty + 1),
           prev_w = LROW(x0 - 1, 2, ty + 1), prev_r = LROW(x0 - 1, 3, ty + 1),
           prev_T = LROW(x0 - 1, 4, ty + 1), prev_c = LROW(x0 - 1, 5, ty + 1);
    __syncthreads();   // all reads of slot(x0-1) done before iter 0 overwrites it

    float4 du4, dv4, dw4, drou, dT4, dc4;  // results carried one iteration

#pragma unroll 1
    for (int i = 0; i < MARCH; ++i) {
        const int P = x0 + i, Pp = P + 1;

        // Stage plane P+2 into slot(P+2)==slot(P-1) (dead: carried in regs).
        // Overlaps this plane's compute; drained by the end-of-iter barrier.
        if (i < MARCH - 1)
            stage_plane(sb, smem, P + 2, y0, tx, ty);

        // Store previous plane's results (aged one full phase in regs).
        if (i > 0) {
            const int b4p = ((P - 1) * XS + y * YS) / 4 + tx;
            st_nt(du4,  o4 + b4p);
            st_nt(dv4,  o4 + b4p + fs4);
            st_nt(dw4,  o4 + b4p + 2 * fs4);
            st_nt(drou, o4 + b4p + 3 * fs4);
            st_nt(dT4,  o4 + b4p + 4 * fs4);
            st_nt(dc4,  o4 + b4p + 5 * fs4);
        }

        // ---- compute plane P ----
        const float4 u_c = LROW(P, 0, ty + 1), v_c = LROW(P, 1, ty + 1),
                     w_c = LROW(P, 2, ty + 1), r_c = LROW(P, 3, ty + 1),
                     T_c = LROW(P, 4, ty + 1), c_c = LROW(P, 5, ty + 1);

        float4 inv_r;
        inv_r.x = 1.0f / r_c.x; inv_r.y = 1.0f / r_c.y;
        inv_r.z = 1.0f / r_c.z; inv_r.w = 1.0f / r_c.w;

        NEIGH(T, 4)
        DERIVS(T)
        NEIGH(r, 3)

        float4 p_c, p_xm, p_xp, p_ym, p_yp;
#define PC(C) \
        p_c.C  = Rgas * r_c.C    * T_c.C; \
        p_xm.C = Rgas * prev_r.C * prev_T.C; \
        p_xp.C = Rgas * r_xp.C   * T_xp.C; \
        p_ym.C = Rgas * r_ym.C   * T_ym.C; \
        p_yp.C = Rgas * r_yp.C   * T_yp.C;
        PC(x) PC(y) PC(z) PC(w)
#undef PC
        const float p_zm = __shfl_up(p_c.w, 1, 32);
        const float p_zp = __shfl_down(p_c.x, 1, 32);

        float4 dpdx, dpdy, dpdz;
#define DP(C) \
        dpdx.C = (p_xp.C - p_xm.C) * inv2dx; \
        dpdy.C = (p_yp.C - p_ym.C) * inv2dy;
        DP(x) DP(y) DP(z) DP(w)
#undef DP
        dpdz.x = (p_c.y - p_zm) * inv2dz;
        dpdz.y = (p_c.z - p_c.x) * inv2dz;
        dpdz.z = (p_c.w - p_c.y) * inv2dz;
        dpdz.w = (p_zp  - p_c.z) * inv2dz;

        NEIGH(u, 0)
        DERIVS(u)
#define DR(C) drou.C = -(r_xp.C * u_xp.C - prev_r.C * prev_u.C) * inv2dx;
        DR(x) DR(y) DR(z) DR(w)
#undef DR

        NEIGH(v, 1)
        DERIVS(v)

        NEIGH(w, 2)
        DERIVS(w)

        NEIGH(c, 5)
        DERIVS(c)
        (void)lap_c;

#define OUT(C) \
        du4.C = (-dpdx.C + MUc * lap_u.C) * inv_r.C - adv_u.C; \
        dv4.C = (-dpdy.C + MUc * lap_v.C) * inv_r.C - adv_v.C; \
        dw4.C = (-Gc * r_c.C - dpdz.C + MUc * lap_w.C) * inv_r.C - adv_w.C; \
        dT4.C = KTHc * lap_T.C * inv_r.C * invCV - adv_T.C; \
        dc4.C = -adv_c.C;
        OUT(x) OUT(y) OUT(z) OUT(w)
#undef OUT

        // z-wall fixes: tx 0 comp .x is z=0, tx 31 comp .w is z=127
        if (tx == 0) {
            du4.x = 0.0f; dv4.x = 0.0f; dw4.x = 0.0f; dT4.x = 0.0f;
            const float dzc0 = (-3.0f * c_c.x + 4.0f * c_c.y - c_c.z) * inv2dz;
            dc4.x = -(u_c.x * (c_xp.x - prev_c.x) * inv2dx
                    + v_c.x * (c_yp.x - c_ym.x) * inv2dy
                    + w_c.x * dzc0);
        }
        if (tx == 31) {
            du4.w = 0.0f; dv4.w = 0.0f; dw4.w = 0.0f; dT4.w = 0.0f;
            const float dzcN = (3.0f * c_c.w - 4.0f * c_c.z + c_c.y) * inv2dz;
            dc4.w = -(u_c.w * (c_xp.w - prev_c.w) * inv2dx
                    + v_c.w * (c_yp.w - c_ym.w) * inv2dy
                    + w_c.w * dzcN);
        }

        // Carry this plane's centers as next iteration's xm.
        prev_u = u_c; prev_v = v_c; prev_w = w_c;
        prev_r = r_c; prev_T = T_c; prev_c = c_c;

        // Drains vmcnt once: stage(P+2) (issued one compute phase ago) and
        // the stores; also fences slot reuse for the next iteration.
        __syncthreads();
    }

    // epilogue: store last plane
    {
        const int b4p = ((x0 + MARCH - 1) * XS + y * YS) / 4 + tx;
        st_nt(du4,  o4 + b4p);
        st_nt(dv4,  o4 + b4p + fs4);
        st_nt(dw4,  o4 + b4p + 2 * fs4);
        st_nt(drou, o4 + b4p + 3 * fs4);
        st_nt(dT4,  o4 + b4p + 4 * fs4);
        st_nt(dc4,  o4 + b4p + 5 * fs4);
    }
}

extern "C" void kernel_launch(void* const* d_in, const int* in_sizes, int n_in,
                              void* d_out, int out_size, void* d_ws, size_t ws_size,
                              hipStream_t stream) {
    (void)in_sizes; (void)n_in; (void)d_ws; (void)ws_size; (void)out_size;
    const float* s = (const float*)d_in[0];
    float* o = (float*)d_out;

    dim3 block(32, BYt, 1);                 // 32 z-quads x 4 y rows = 128 thr
    dim3 grid(NYc / BYt, NXc / MARCH, 1);   // 64 y-tiles x 4 x-tiles = 256 blocks
    rb_kernel<<<grid, block, 0, stream>>>(s, o);
}